// Round 1
// baseline (803.217 us; speedup 1.0000x reference)
//
#include <hip/hip_runtime.h>

#define IN_F 4096
#define OUT_F 16384
#define MTOK 8192   // B*S = 4*2048

#define GBM 128
#define GBN 128
#define GBK 64

typedef __attribute__((ext_vector_type(4))) int   i32x4;
typedef __attribute__((ext_vector_type(4))) float f32x4;

__device__ __forceinline__ void gload_lds16(const void* g, void* lds) {
    __builtin_amdgcn_global_load_lds(
        (const __attribute__((address_space(1))) void*)g,
        (__attribute__((address_space(3))) void*)lds,
        16, 0, 0);
}

// ---------------------------------------------------------------------------
// Kernel 1: per-token absmax -> int8 quantize x, store scale
// one block per token (row of 4096 f32)
// ---------------------------------------------------------------------------
__global__ __launch_bounds__(256) void k_quant(const float* __restrict__ x,
                                               char* __restrict__ xq,
                                               float* __restrict__ xs) {
    const int m = blockIdx.x;
    const int t = threadIdx.x;
    const float* xrow = x + (size_t)m * IN_F;

    f32x4 v[4];
    float mx = 0.f;
#pragma unroll
    for (int i = 0; i < 4; ++i) {
        v[i] = *(const f32x4*)&xrow[(i * 256 + t) * 4];
        mx = fmaxf(mx, fmaxf(fmaxf(fabsf(v[i].x), fabsf(v[i].y)),
                             fmaxf(fabsf(v[i].z), fabsf(v[i].w))));
    }
#pragma unroll
    for (int off = 32; off > 0; off >>= 1)
        mx = fmaxf(mx, __shfl_xor(mx, off));

    __shared__ float wmax[4];
    const int wid = t >> 6;
    if ((t & 63) == 0) wmax[wid] = mx;
    __syncthreads();
    const float scale = fmaxf(fmaxf(fmaxf(wmax[0], wmax[1]),
                                    fmaxf(wmax[2], wmax[3])), 1e-5f);
    const float inv = 127.0f / scale;

    int* xqi = (int*)(xq + (size_t)m * IN_F);
#pragma unroll
    for (int i = 0; i < 4; ++i) {
        // rintf = round-half-even, matches jnp.round
        int q0 = (int)rintf(fminf(fmaxf(v[i].x * inv, -128.f), 127.f));
        int q1 = (int)rintf(fminf(fmaxf(v[i].y * inv, -128.f), 127.f));
        int q2 = (int)rintf(fminf(fmaxf(v[i].z * inv, -128.f), 127.f));
        int q3 = (int)rintf(fminf(fmaxf(v[i].w * inv, -128.f), 127.f));
        xqi[i * 256 + t] = (q0 & 255) | ((q1 & 255) << 8) |
                           ((q2 & 255) << 16) | (q3 << 24);
    }
    if (t == 0) xs[m] = scale;
}

// ---------------------------------------------------------------------------
// Kernel 2: ternary int32 weights -> int8 pack
// ---------------------------------------------------------------------------
__global__ __launch_bounds__(256) void k_wconv(const int* __restrict__ wt,
                                               int* __restrict__ w8) {
    const int total4 = OUT_F * IN_F / 4;  // 16,777,216 packed dwords
    int idx = blockIdx.x * 256 + threadIdx.x;
    const int stride = gridDim.x * 256;
    for (; idx < total4; idx += stride) {
        i32x4 w = *(const i32x4*)&wt[(size_t)idx * 4];
        w8[idx] = (w.x & 255) | ((w.y & 255) << 8) |
                  ((w.z & 255) << 16) | (w.w << 24);
    }
}

// ---------------------------------------------------------------------------
// Kernel 3: int8 GEMM, C[m][n] = (sum_k q[m][k]*t[n][k]) * xs[m] * wsc/127
// 128x128 tile, BK=64, 4 waves (2x2, each 64x64), mfma_i32_16x16x64_i8
// m97-style structure: global_load_lds width-16 staging + 2 barriers / K-step
// ---------------------------------------------------------------------------
__global__ __launch_bounds__(256, 2) void k_gemm(
    const char*  __restrict__ Aq,     // [MTOK][IN_F] int8
    const char*  __restrict__ Bq,     // [OUT_F][IN_F] int8
    const float* __restrict__ xs,     // [MTOK]
    const float* __restrict__ wsp,    // [1] weight scale
    float*       __restrict__ C) {    // [MTOK][OUT_F]
    __shared__ __align__(16) char sA[GBM * GBK];   // 8 KB
    __shared__ __align__(16) char sB[GBN * GBK];   // 8 KB

    const int t    = threadIdx.x;
    const int lane = t & 63;
    const int wid  = t >> 6;

    const int nTilesN = OUT_F / GBN;              // 128
    const int bm = blockIdx.x / nTilesN;
    const int bn = blockIdx.x % nTilesN;
    const int mBase = bm * GBM;
    const int nBase = bn * GBN;

    const int wm = (wid >> 1) * 64;               // wave tile origin in M
    const int wn = (wid & 1) * 64;                // wave tile origin in N

    // staging: byte p = j*4096 + wid*1024 + lane*16 ; row = p>>6, col = p&63
    const int p0 = wid * 1024 + lane * 16;
    const int r0 = p0 >> 6, c0 = p0 & 63;
    const int r1 = r0 + 64;                       // p1 = p0 + 4096, col same
    const char* Ag0 = Aq + (size_t)(mBase + r0) * IN_F + c0;
    const char* Ag1 = Aq + (size_t)(mBase + r1) * IN_F + c0;
    const char* Bg0 = Bq + (size_t)(nBase + r0) * IN_F + c0;
    const char* Bg1 = Bq + (size_t)(nBase + r1) * IN_F + c0;

    i32x4 acc[4][4];
#pragma unroll
    for (int i = 0; i < 4; ++i)
#pragma unroll
        for (int j = 0; j < 4; ++j)
            acc[i][j] = (i32x4){0, 0, 0, 0};

    const int arow = (wm + (lane & 15)) * GBK + (lane >> 4) * 16;
    const int brow = (wn + (lane & 15)) * GBK + (lane >> 4) * 16;

    for (int k0 = 0; k0 < IN_F; k0 += GBK) {
        gload_lds16(Ag0 + k0, sA + wid * 1024);
        gload_lds16(Ag1 + k0, sA + 4096 + wid * 1024);
        gload_lds16(Bg0 + k0, sB + wid * 1024);
        gload_lds16(Bg1 + k0, sB + 4096 + wid * 1024);
        __syncthreads();   // compiler drains vmcnt before barrier

        i32x4 af[4], bf[4];
#pragma unroll
        for (int i = 0; i < 4; ++i)
            af[i] = *(const i32x4*)&sA[arow + i * 16 * GBK];
#pragma unroll
        for (int i = 0; i < 4; ++i)
            bf[i] = *(const i32x4*)&sB[brow + i * 16 * GBK];

#pragma unroll
        for (int mi = 0; mi < 4; ++mi)
#pragma unroll
            for (int ni = 0; ni < 4; ++ni)
                acc[mi][ni] = __builtin_amdgcn_mfma_i32_16x16x64_i8(
                    af[mi], bf[ni], acc[mi][ni], 0, 0, 0);

        __syncthreads();   // protect LDS from next iteration's staging
    }

    // epilogue: D row = (lane>>4)*4 + r, col = lane&15 (m89-verified mapping)
    const float wsc = wsp[0] * (1.0f / 127.0f);
    float rs[4][4];
#pragma unroll
    for (int mi = 0; mi < 4; ++mi)
#pragma unroll
        for (int r = 0; r < 4; ++r)
            rs[mi][r] = xs[mBase + wm + mi * 16 + (lane >> 4) * 4 + r] * wsc;

#pragma unroll
    for (int mi = 0; mi < 4; ++mi) {
#pragma unroll
        for (int ni = 0; ni < 4; ++ni) {
#pragma unroll
            for (int r = 0; r < 4; ++r) {
                const int row = mBase + wm + mi * 16 + (lane >> 4) * 4 + r;
                const int col = nBase + wn + ni * 16 + (lane & 15);
                C[(size_t)row * OUT_F + col] = (float)acc[mi][ni][r] * rs[mi][r];
            }
        }
    }
}

// ---------------------------------------------------------------------------
extern "C" void kernel_launch(void* const* d_in, const int* in_sizes, int n_in,
                              void* d_out, int out_size, void* d_ws, size_t ws_size,
                              hipStream_t stream) {
    const float* x   = (const float*)d_in[0];     // [4,2048,4096] f32
    const int*   wt  = (const int*)d_in[1];       // [16384,4096] int32 ternary
    const float* wsp = (const float*)d_in[2];     // [1] f32 scale
    float* out = (float*)d_out;                   // [4,2048,16384] f32

    // workspace layout
    char*  w8 = (char*)d_ws;                                   // 64 MB
    char*  xq = (char*)d_ws + (size_t)OUT_F * IN_F;            // 32 MB
    float* xs = (float*)((char*)d_ws + (size_t)OUT_F * IN_F
                                     + (size_t)MTOK * IN_F);   // 32 KB

    k_wconv<<<8192, 256, 0, stream>>>(wt, (int*)w8);
    k_quant<<<MTOK, 256, 0, stream>>>(x, xq, xs);

    const int grid = (MTOK / GBM) * (OUT_F / GBN);  // 64 * 128 = 8192
    k_gemm<<<grid, 256, 0, stream>>>(xq, w8, xs, wsp, out);
}